// Round 11
// baseline (1012.491 us; speedup 1.0000x reference)
//
#include <hip/hip_runtime.h>
#include <hip/hip_bf16.h>
#include <stdint.h>

#define BB 4
#define SS 1024
#define DIM 2048
#define NH 16
#define QR 1024
#define KVR 512
#define NOPE 128
#define ROPE 64
#define VH 128
#define QKH 192
#define NTOK 4096

static constexpr float SCALE_ = 0.07216878364870322f; // 192^-0.5
static constexpr float EPS_ = 1e-6f;

typedef unsigned short u16;
typedef unsigned int u32;
using f32x4  = __attribute__((ext_vector_type(4))) float;
using bf16x8 = __attribute__((ext_vector_type(8))) __bf16;

#define MFMA16 __builtin_amdgcn_mfma_f32_16x16x32_bf16

__device__ __forceinline__ u16 f2b(float f) {
  u32 u = __float_as_uint(f);
  u32 r = u + 0x7fffu + ((u >> 16) & 1u);   // RNE
  return (u16)(r >> 16);
}
__device__ __forceinline__ u32 pk2(float a, float b) {
  return (u32)f2b(a) | ((u32)f2b(b) << 16);
}
__device__ __forceinline__ float b2f(u32 hi16) {
  return __uint_as_float(hi16 << 16);
}
__device__ __forceinline__ void gll16(const u16* g, u16* l) {
  __builtin_amdgcn_global_load_lds(
      (const __attribute__((address_space(1))) void*)g,
      (__attribute__((address_space(3))) void*)l, 16, 0, 0);
}

// ---------------- f32 -> bf16 convert (8 elems/thread) ----------------
__global__ __launch_bounds__(256) void cvt_bf16(const float* __restrict__ in,
                                                u16* __restrict__ out, int n) {
  int i = (blockIdx.x * 256 + threadIdx.x) * 8;
  if (i >= n) return;
  float4 a = *(const float4*)&in[i];
  float4 b = *(const float4*)&in[i + 4];
  uint4 o;
  o.x = pk2(a.x, a.y); o.y = pk2(a.z, a.w);
  o.z = pk2(b.x, b.y); o.w = pk2(b.z, b.w);
  *(uint4*)&out[i] = o;
}

// ---------------- wkv_b split: wb_k transposed per head, wb_v straight ----------------
__global__ __launch_bounds__(256) void prep_wkvb(const float* __restrict__ w,
                                                 u16* __restrict__ wbkt,
                                                 u16* __restrict__ wbv) {
  int idx = blockIdx.x * 256 + threadIdx.x;   // over 16*256*512
  int c = idx & 511;
  int rowh = idx >> 9;
  int h = rowh >> 8;
  int dr = rowh & 255;
  float v = w[idx];
  if (dr < NOPE) wbkt[((h * KVR + c) << 7) + dr] = f2b(v);           // (NH,512,128)
  else           wbv[((h * VH + (dr - NOPE)) << 9) + c] = f2b(v);    // (NH,128,512)
}

// ---------------- RMSNorm over 1024 (q path) ----------------
__global__ __launch_bounds__(256) void rms_q_kernel(const float* __restrict__ X,
                                                    const float* __restrict__ w,
                                                    u16* __restrict__ out) {
  int r = blockIdx.x, tid = threadIdx.x;
  const float4 v = *(const float4*)&X[(long)r * QR + tid * 4];
  float ss = v.x * v.x + v.y * v.y + v.z * v.z + v.w * v.w;
  for (int m = 1; m < 64; m <<= 1) ss += __shfl_xor(ss, m);
  __shared__ float red[4];
  if ((tid & 63) == 0) red[tid >> 6] = ss;
  __syncthreads();
  float tot = red[0] + red[1] + red[2] + red[3];
  float sc = rsqrtf(tot / QR + EPS_);
  float4 wv = *(const float4*)&w[tid * 4];
  uint2 o;
  o.x = pk2(v.x * sc * wv.x, v.y * sc * wv.y);
  o.y = pk2(v.z * sc * wv.z, v.w * sc * wv.w);
  *(uint2*)&out[(long)r * QR + tid * 4] = o;
}

// ---------------- q post (bf16 input): split nope / rope(pe)*SCALE, head-major ----------------
__global__ __launch_bounds__(256) void post_q_kernel(const u16* __restrict__ C2,
                                                     const float* __restrict__ fc,
                                                     const float* __restrict__ fs,
                                                     u16* __restrict__ qn,
                                                     u16* __restrict__ qp) {
  int r = blockIdx.x, tid = threadIdx.x;
  int s = r & (SS - 1);
  const u16* row = C2 + (long)r * (NH * QKH);
  for (int j = tid; j < NH * QKH / 2; j += 256) {
    int col = j * 2;
    int h = col / QKH;
    int dd = col - h * QKH;
    u32 pair = *(const u32*)&row[col];
    if (dd < NOPE) {
      *(u32*)&qn[((long)h * NTOK + r) * NOPE + dd] = pair;   // already bf16
    } else {
      float x0 = b2f(pair & 0xffffu), x1 = b2f(pair >> 16);
      int jr = (dd - NOPE) >> 1;
      float c = fc[s * 32 + jr], sn = fs[s * 32 + jr];
      *(u32*)&qp[((long)h * NTOK + r) * ROPE + (dd - NOPE)] =
          pk2((x0 * c - x1 * sn) * SCALE_, (x0 * sn + x1 * c) * SCALE_);
    }
  }
}

// ---------------- kv post: rmsnorm(512) -> kv_sw (XOR-swizzled) + v8 (k-subtiled), rope k_pe_sw ----
__global__ __launch_bounds__(256) void post_kv_kernel(const float* __restrict__ C3,
                                                      const float* __restrict__ w,
                                                      const float* __restrict__ fc,
                                                      const float* __restrict__ fs,
                                                      u16* __restrict__ kv_sw,
                                                      u16* __restrict__ v8,
                                                      u16* __restrict__ kpe_sw) {
  int r = blockIdx.x, tid = threadIdx.x;
  int b = r >> 10, t = r & (SS - 1);
  const float* row = C3 + (long)r * 576;
  float2 v = *(const float2*)&row[tid * 2];
  float ss = v.x * v.x + v.y * v.y;
  for (int m = 1; m < 64; m <<= 1) ss += __shfl_xor(ss, m);
  __shared__ float red[4];
  if ((tid & 63) == 0) red[tid >> 6] = ss;
  __syncthreads();
  float tot = red[0] + red[1] + red[2] + red[3];
  float sc = rsqrtf(tot / KVR + EPS_);
  int c = tid * 2;
  int xm = (t & 7) << 3;
  float y0 = v.x * sc * w[c], y1 = v.y * sc * w[c + 1];
  *(u32*)&kv_sw[((long)b * SS + t) * KVR + (c ^ xm)] = pk2(y0, y1);
  long o8 = (long)b * SS * KVR + ((long)(t >> 3) * 512 + c) * 8 + (t & 7);
  v8[o8]     = f2b(y0);
  v8[o8 + 8] = f2b(y1);
  if (tid < 32) {
    float x0 = row[KVR + tid * 2], x1 = row[KVR + tid * 2 + 1];
    float cc = fc[t * 32 + tid], sn = fs[t * 32 + tid];
    *(u32*)&kpe_sw[((long)b * SS + t) * ROPE + ((tid * 2) ^ xm)] =
        pk2(x0 * cc - x1 * sn, x0 * sn + x1 * cc);
  }
}

// ---------------- GEMM: C(M,N) = A(M,K) * B(N,K)^T, bf16 in, f32/bf16 out ----------------
template <bool CBF16>
__global__ __launch_bounds__(256) void gemm_bt(const u16* __restrict__ Ag,
                                               const u16* __restrict__ Bg,
                                               void* __restrict__ Cg,
                                               int M, int N, int K,
                                               int lda, int ldb, int ldc,
                                               long sA, long sB, long sC,
                                               float oscale) {
  const u16* A = Ag + (long)blockIdx.z * sA;
  const u16* Bm = Bg + (long)blockIdx.z * sB;
  const int row0 = blockIdx.y * 128;
  const int col0 = blockIdx.x * 128;
  const int tid = threadIdx.x;
  const int wave = tid >> 6, lane = tid & 63;
  const int g = lane >> 4, r = lane & 15;
  const int wr = wave >> 1, wc = wave & 1;

  __shared__ u16 As[2][128 * 32];
  __shared__ u16 Bs[2][128 * 32];

  f32x4 acc[4][4] = {};
  const int nk = K >> 5;

  auto stage = [&](int kt, int p) {
    int k0 = kt << 5;
#pragma unroll
    for (int j = 0; j < 2; ++j) {
      int ldsoff = (j * 4096 + wave * 1024) >> 1;
      int rowi = j * 64 + wave * 16 + (lane >> 2);
      int coli = (lane & 3) << 3;
      const u16* ga = A + (long)(row0 + rowi) * lda + k0 + coli;
      gll16(ga, &As[p][ldsoff]);
      int rb = col0 + rowi; if (rb > N - 1) rb = N - 1;
      const u16* gb = Bm + (long)rb * ldb + k0 + coli;
      gll16(gb, &Bs[p][ldsoff]);
    }
  };

  stage(0, 0);
  for (int kt = 0; kt < nk; ++kt) {
    __syncthreads();
    if (kt + 1 < nk) stage(kt + 1, (kt + 1) & 1);
    const int p = kt & 1;
    bf16x8 af[4], bf[4];
#pragma unroll
    for (int i = 0; i < 4; i++) {
      af[i] = *(const bf16x8*)&As[p][(wr * 64 + i * 16 + r) * 32 + g * 8];
      bf[i] = *(const bf16x8*)&Bs[p][(wc * 64 + i * 16 + r) * 32 + g * 8];
    }
#pragma unroll
    for (int i = 0; i < 4; i++)
#pragma unroll
      for (int j = 0; j < 4; j++)
        acc[i][j] = MFMA16(af[i], bf[j], acc[i][j], 0, 0, 0);
  }

#pragma unroll
  for (int i = 0; i < 4; i++)
#pragma unroll
    for (int j = 0; j < 4; j++) {
      int rowb = row0 + wr * 64 + i * 16 + g * 4;
      int colc = col0 + wc * 64 + j * 16 + r;
      if (colc < N) {
        if constexpr (CBF16) {
          u16* C = (u16*)Cg + (long)blockIdx.z * sC;
#pragma unroll
          for (int e = 0; e < 4; e++)
            C[(long)(rowb + e) * ldc + colc] = f2b(acc[i][j][e] * oscale);
        } else {
          float* C = (float*)Cg + (long)blockIdx.z * sC;
#pragma unroll
          for (int e = 0; e < 4; e++)
            C[(long)(rowb + e) * ldc + colc] = acc[i][j][e] * oscale;
        }
      }
    }
}

// ---------------- flash attention v10b: defer-rescale + spec-P (l_run tile-0 fix) ----------------
// Round-9 structure (4 waves, 64 rows, 2 blocks/CU). T13 defer-rescale with
// __syncthreads_and vote at B1 (speculative P with old m; in-register correction
// on unstable tiles), nomask fast path (all but last 2 tiles), hoisted XOR bases.
// FIX vs v10: unstable-path l-update distinguishes classic tile 0 (ps vs m_new)
// from speculative tiles (ps vs m_old): l = tt==0 ? ps : alpha*(l+ps).
__global__ __launch_bounds__(256, 2) void attn_kernel(
    const u16* __restrict__ q_lat, const u16* __restrict__ q_pe,
    const u16* __restrict__ kv_sw, const u16* __restrict__ v8g,
    const u16* __restrict__ kpe_sw, u16* __restrict__ o_lat) {
  const int bid = blockIdx.x;
  const int xcd = bid & 7, idx = bid >> 3;
  const int b = xcd >> 1;
  const int h = idx & 15;
  const int jp = (idx >> 4) | ((xcd & 1) << 2);   // 0..7
  const int wv = threadIdx.x >> 6, lane = threadIdx.x & 63;
  const int g = lane >> 4, r = lane & 15;
  const int xm = (r & 7) << 3;
  // hoisted swizzle bases: (c*32+g*8)^xm == (c even ? keb : kob) + c*32
  const int keb = (g * 8) ^ xm;
  const int kob = keb - 2 * (xm & 32);

  __shared__ __attribute__((aligned(16))) u16 Ks[32 * 512];   // 32 KB swz K
  __shared__ __attribute__((aligned(16))) u16 Vs[32 * 512];   // 32 KB subtiled V
  __shared__ __attribute__((aligned(16))) u16 Kp[32 * 64];    // 4 KB swz kpe
  __shared__ __attribute__((aligned(16))) u16 P[64][40];      // 5 KB
  __shared__ float alphab[64];
  __shared__ float lbuf[64];

  const u16* KVg = kv_sw + (long)b * SS * KVR;
  const u16* VGg = v8g   + (long)b * SS * KVR;
  const u16* KPg = kpe_sw + (long)b * SS * ROPE;

  auto stage = [&](int t0) {
#pragma unroll
    for (int i = 0; i < 8; ++i) {
      int row = wv * 8 + i;
      gll16(KVg + (long)(t0 + row) * KVR + lane * 8, &Ks[row * 512]);
      gll16(VGg + (long)t0 * KVR + wv * 4096 + i * 512 + lane * 8,
            &Vs[wv * 4096 + i * 512]);
    }
    gll16(KPg + (long)t0 * ROPE + wv * 512 + lane * 8, &Kp[wv * 512]);
  };

  for (int seg = 0; seg < 2; ++seg) {
    const int j = seg ? jp : (15 - jp);    // big chunk first
    const int qa = j * 64;
    const int nt = 2 * (j + 1);            // 32-key tiles
    const int q_row = qa + wv * 16 + r;

    const u16* Q  = q_lat + ((long)h * NTOK + (long)b * SS + q_row) * KVR;
    const u16* Qp = q_pe  + ((long)h * NTOK + (long)b * SS + q_row) * ROPE;
    bf16x8 qf[18];
#pragma unroll
    for (int c = 0; c < 16; ++c) qf[c] = *(const bf16x8*)&Q[c * 32 + g * 8];
    qf[16] = *(const bf16x8*)&Qp[g * 8];
    qf[17] = *(const bf16x8*)&Qp[32 + g * 8];

    f32x4 acc[4][8];
#pragma unroll
    for (int i = 0; i < 4; i++)
#pragma unroll
      for (int jn = 0; jn < 8; jn++) acc[i][jn] = f32x4{0.f, 0.f, 0.f, 0.f};
    float m_run = -1e30f, l_run = 0.f;

    stage(0);
    __syncthreads();

    for (int tt = 0; tt < nt; ++tt) {
      const int t0 = tt << 5;

      // QK^T over 32 keys (2 row-groups of 16), 18 c-steps, imm-offset addrs
      f32x4 st0 = {0.f, 0.f, 0.f, 0.f}, st1 = {0.f, 0.f, 0.f, 0.f};
#pragma unroll
      for (int c = 0; c < 16; ++c) {
        int off = ((c & 1) ? kob : keb) + c * 32;
        bf16x8 k0 = *(const bf16x8*)&Ks[r * 512 + off];
        bf16x8 k1 = *(const bf16x8*)&Ks[(16 + r) * 512 + off];
        st0 = MFMA16(k0, qf[c], st0, 0, 0, 0);
        st1 = MFMA16(k1, qf[c], st1, 0, 0, 0);
      }
      {
        bf16x8 k0 = *(const bf16x8*)&Kp[r * 64 + keb];
        bf16x8 k1 = *(const bf16x8*)&Kp[(16 + r) * 64 + keb];
        st0 = MFMA16(k0, qf[16], st0, 0, 0, 0);
        st1 = MFMA16(k1, qf[16], st1, 0, 0, 0);
        bf16x8 k2 = *(const bf16x8*)&Kp[r * 64 + kob + 32];
        bf16x8 k3 = *(const bf16x8*)&Kp[(16 + r) * 64 + kob + 32];
        st0 = MFMA16(k2, qf[17], st0, 0, 0, 0);
        st1 = MFMA16(k3, qf[17], st1, 0, 0, 0);
      }

      // V fragments -> regs (must precede B1; stage overwrites Vs)
      bf16x8 vf[8];
#pragma unroll
      for (int nc = 0; nc < 8; ++nc)
        vf[nc] = *(const bf16x8*)&Vs[((g << 9) + (wv << 7) + (nc << 4) + r) << 3];

      // scores -> sv (mask only for last 2 tiles), row max
      float sv[8];
      float smax = -1e30f;
      if (t0 + 31 > qa) {
#pragma unroll
        for (int i = 0; i < 4; i++) {
          int t = t0 + g * 4 + i;
          sv[i]     = (t      <= q_row) ? st0[i] : -1e30f;
          sv[4 + i] = (t + 16 <= q_row) ? st1[i] : -1e30f;
          smax = fmaxf(smax, fmaxf(sv[i], sv[4 + i]));
        }
      } else {
#pragma unroll
        for (int i = 0; i < 4; i++) {
          sv[i] = st0[i]; sv[4 + i] = st1[i];
          smax = fmaxf(smax, fmaxf(sv[i], sv[4 + i]));
        }
      }
      smax = fmaxf(smax, __shfl_xor(smax, 16));
      smax = fmaxf(smax, __shfl_xor(smax, 32));

      float m_new = fmaxf(m_run, smax);
      float alpha = __expf(m_run - m_new);
      int pred;
      float ps = 0.f;
      if (tt == 0) {          // classic (m_run = -inf; correction impossible)
        pred = 0;
#pragma unroll
        for (int i = 0; i < 8; i++) { sv[i] = __expf(sv[i] - m_new); ps += sv[i]; }
      } else {                // speculative with OLD m (bounded by clamp)
        pred = (smax - m_run <= 8.0f);
#pragma unroll
        for (int i = 0; i < 8; i++) {
          sv[i] = __expf(fminf(sv[i] - m_run, 85.0f)); ps += sv[i];
        }
      }
      ps += __shfl_xor(ps, 16);
      ps += __shfl_xor(ps, 32);

      {
        uint2 pw0, pw1;
        pw0.x = pk2(sv[0], sv[1]); pw0.y = pk2(sv[2], sv[3]);
        pw1.x = pk2(sv[4], sv[5]); pw1.y = pk2(sv[6], sv[7]);
        *(uint2*)&P[wv * 16 + r][g * 4]      = pw0;
        *(uint2*)&P[wv * 16 + r][16 + g * 4] = pw1;
      }
      if (g == 0) alphab[wv * 16 + r] = alpha;

      int vote = __syncthreads_and(pred);    // B1 + stability vote
      if (tt + 1 < nt) stage(t0 + 32);       // overwrite K/V/kpe; drained at B2

      if (vote) {
        l_run += ps;                         // m_run unchanged; no rescale
#pragma unroll
        for (int mc = 0; mc < 4; ++mc) {
          bf16x8 pa = *(const bf16x8*)&P[mc * 16 + r][g * 8];
#pragma unroll
          for (int nc = 0; nc < 8; ++nc)
            acc[mc][nc] = MFMA16(pa, vf[nc], acc[mc][nc], 0, 0, 0);
        }
      } else {
        if (tt > 0) {                        // correct P in registers, rewrite
#pragma unroll
          for (int i = 0; i < 8; i++) sv[i] *= alpha;
          uint2 pw0, pw1;
          pw0.x = pk2(sv[0], sv[1]); pw0.y = pk2(sv[2], sv[3]);
          pw1.x = pk2(sv[4], sv[5]); pw1.y = pk2(sv[6], sv[7]);
          *(uint2*)&P[wv * 16 + r][g * 4]      = pw0;
          *(uint2*)&P[wv * 16 + r][16 + g * 4] = pw1;
        }
        m_run = m_new;
        // FIX: tile 0's ps is already relative to m_new (classic path) — do NOT
        // scale it by alpha (alpha==0 there zeroed l and produced inf/NaN).
        l_run = (tt == 0) ? ps : alpha * (l_run + ps);
        __syncthreads();                     // corrected P visible
#pragma unroll
        for (int mc = 0; mc < 4; ++mc) {
          bf16x8 pa = *(const bf16x8*)&P[mc * 16 + r][g * 8];
          f32x4 a4 = *(const f32x4*)&alphab[mc * 16 + g * 4];
#pragma unroll
          for (int nc = 0; nc < 8; ++nc) {
            f32x4 t = acc[mc][nc] * a4;
            acc[mc][nc] = MFMA16(pa, vf[nc], t, 0, 0, 0);
          }
        }
      }
      __syncthreads();                       // B2: stage drained; P rewritable
    }

    if (g == 0) lbuf[wv * 16 + r] = l_run;
    __syncthreads();
    u16* O = o_lat + ((long)h * NTOK + (long)b * SS + qa) * KVR;
#pragma unroll
    for (int mc = 0; mc < 4; ++mc) {
      f32x4 li = *(const f32x4*)&lbuf[mc * 16 + g * 4];
#pragma unroll
      for (int e = 0; e < 4; e++) li[e] = 1.f / li[e];
#pragma unroll
      for (int nc = 0; nc < 8; ++nc) {
        int col = wv * 128 + nc * 16 + r;
#pragma unroll
        for (int e = 0; e < 4; e++)
          O[(long)(mc * 16 + g * 4 + e) * KVR + col] = f2b(acc[mc][nc][e] * li[e]);
      }
    }
    __syncthreads();                         // lbuf/LDS safe for next seg
  }
}

// ---------------- host launch ----------------
extern "C" void kernel_launch(void* const* d_in, const int* in_sizes, int n_in,
                              void* d_out, int out_size, void* d_ws, size_t ws_size,
                              hipStream_t stream) {
  (void)in_sizes; (void)n_in; (void)out_size; (void)ws_size;
  const float* x    = (const float*)d_in[0];
  const float* fc   = (const float*)d_in[2];
  const float* fs   = (const float*)d_in[3];
  const float* wqa  = (const float*)d_in[4];
  const float* qnw  = (const float*)d_in[5];
  const float* wqb  = (const float*)d_in[6];
  const float* wkva = (const float*)d_in[7];
  const float* kvnw = (const float*)d_in[8];
  const float* wkvb = (const float*)d_in[9];
  const float* wo   = (const float*)d_in[10];
  float* out = (float*)d_out;

  char* w = (char*)d_ws;
  size_t off = 0;
  auto alloc = [&](size_t bytes) {
    void* p = w + off;
    off += (bytes + 255) & ~(size_t)255;
    return p;
  };
  // ---- persistent region ----
  u16* wbkt   = (u16*)alloc((size_t)NH * KVR * NOPE * 2);
  u16* wbv    = (u16*)alloc((size_t)NH * VH * KVR * 2);
  u16* wo_b   = (u16*)alloc((size_t)DIM * DIM * 2);
  u16* qnope  = (u16*)alloc((size_t)NH * NTOK * NOPE * 2);
  u16* qpe    = (u16*)alloc((size_t)NH * NTOK * ROPE * 2);
  u16* kv_sw  = (u16*)alloc((size_t)BB * SS * KVR * 2);
  u16* v8b    = (u16*)alloc((size_t)BB * SS * KVR * 2);
  u16* kpe_sw = (u16*)alloc((size_t)BB * SS * ROPE * 2);
  u16* oflat  = (u16*)alloc((size_t)NTOK * DIM * 2);
  // ---- transient region, later overlaid by qlat/olat ----
  u16* qlat   = (u16*)(w + off);            // overlay base
  u16* olat   = qlat;                       // attention writes O in-place over Q
  u16* x_bf   = (u16*)alloc((size_t)NTOK * DIM * 2);
  u16* wqa_b  = (u16*)alloc((size_t)QR * DIM * 2);
  u16* wqb_b  = (u16*)alloc((size_t)NH * QKH * QR * 2);
  u16* wkva_b = (u16*)alloc((size_t)576 * DIM * 2);
  u16* qn     = (u16*)alloc((size_t)NTOK * QR * 2);
  float* C1   = (float*)alloc((size_t)NTOK * QR * 4);
  u16* C2b    = (u16*)alloc((size_t)NTOK * NH * QKH * 2);

  cvt_bf16<<<(NTOK * DIM) / 2048, 256, 0, stream>>>(x, x_bf, NTOK * DIM);
  cvt_bf16<<<(QR * DIM) / 2048, 256, 0, stream>>>(wqa, wqa_b, QR * DIM);
  cvt_bf16<<<(NH * QKH * QR) / 2048, 256, 0, stream>>>(wqb, wqb_b, NH * QKH * QR);
  cvt_bf16<<<(576 * DIM) / 2048, 256, 0, stream>>>(wkva, wkva_b, 576 * DIM);
  cvt_bf16<<<(DIM * DIM) / 2048, 256, 0, stream>>>(wo, wo_b, DIM * DIM);
  prep_wkvb<<<(NH * 256 * KVR) / 256, 256, 0, stream>>>(wkvb, wbkt, wbv);

  gemm_bt<false><<<dim3(QR / 128, NTOK / 128, 1), 256, 0, stream>>>(
      x_bf, wqa_b, C1, NTOK, QR, DIM, DIM, DIM, QR, 0, 0, 0, 1.f);
  rms_q_kernel<<<NTOK, 256, 0, stream>>>(C1, qnw, qn);
  gemm_bt<true><<<dim3(NH * QKH / 128, NTOK / 128, 1), 256, 0, stream>>>(
      qn, wqb_b, C2b, NTOK, NH * QKH, QR, QR, QR, NH * QKH, 0, 0, 0, 1.f);
  post_q_kernel<<<NTOK, 256, 0, stream>>>(C2b, fc, fs, qnope, qpe);
  gemm_bt<false><<<dim3(5, NTOK / 128, 1), 256, 0, stream>>>(
      x_bf, wkva_b, C1, NTOK, 576, DIM, DIM, DIM, 576, 0, 0, 0, 1.f);
  post_kv_kernel<<<NTOK, 256, 0, stream>>>(C1, kvnw, fc, fs, kv_sw, v8b, kpe_sw);
  // q_lat pre-scaled by SCALE_ (softmax scale folded into Q)
  gemm_bt<true><<<dim3(KVR / 128, NTOK / 128, NH), 256, 0, stream>>>(
      qnope, wbkt, qlat, NTOK, KVR, NOPE, NOPE, NOPE, KVR,
      (long)NTOK * NOPE, (long)KVR * NOPE, (long)NTOK * KVR, SCALE_);
  attn_kernel<<<dim3(512, 1, 1), 256, 0, stream>>>(
      qlat, qpe, kv_sw, v8b, kpe_sw, olat);
  gemm_bt<true><<<dim3(1, NTOK / 128, NH), 256, 0, stream>>>(
      olat, wbv, oflat, NTOK, VH, KVR, KVR, KVR, DIM,
      (long)NTOK * KVR, (long)VH * KVR, (long)VH, 1.f);
  gemm_bt<false><<<dim3(DIM / 128, NTOK / 128, 1), 256, 0, stream>>>(
      oflat, wo_b, out, NTOK, DIM, DIM, DIM, DIM, DIM, 0, 0, 0, 1.f);
}

// Round 12
// 447.060 us; speedup vs baseline: 2.2648x; 2.2648x over previous
//
#include <hip/hip_runtime.h>
#include <hip/hip_bf16.h>
#include <stdint.h>

#define BB 4
#define SS 1024
#define DIM 2048
#define NH 16
#define QR 1024
#define KVR 512
#define NOPE 128
#define ROPE 64
#define VH 128
#define QKH 192
#define NTOK 4096

static constexpr float SCALE_ = 0.07216878364870322f; // 192^-0.5
static constexpr float EPS_ = 1e-6f;

typedef unsigned short u16;
typedef unsigned int u32;
using f32x4  = __attribute__((ext_vector_type(4))) float;
using bf16x8 = __attribute__((ext_vector_type(8))) __bf16;

#define MFMA16 __builtin_amdgcn_mfma_f32_16x16x32_bf16

__device__ __forceinline__ u16 f2b(float f) {
  u32 u = __float_as_uint(f);
  u32 r = u + 0x7fffu + ((u >> 16) & 1u);   // RNE
  return (u16)(r >> 16);
}
__device__ __forceinline__ u32 pk2(float a, float b) {
  return (u32)f2b(a) | ((u32)f2b(b) << 16);
}
__device__ __forceinline__ float b2f(u32 hi16) {
  return __uint_as_float(hi16 << 16);
}
__device__ __forceinline__ void gll16(const u16* g, u16* l) {
  __builtin_amdgcn_global_load_lds(
      (const __attribute__((address_space(1))) void*)g,
      (__attribute__((address_space(3))) void*)l, 16, 0, 0);
}

// ---------------- f32 -> bf16 convert (8 elems/thread) ----------------
__global__ __launch_bounds__(256) void cvt_bf16(const float* __restrict__ in,
                                                u16* __restrict__ out, int n) {
  int i = (blockIdx.x * 256 + threadIdx.x) * 8;
  if (i >= n) return;
  float4 a = *(const float4*)&in[i];
  float4 b = *(const float4*)&in[i + 4];
  uint4 o;
  o.x = pk2(a.x, a.y); o.y = pk2(a.z, a.w);
  o.z = pk2(b.x, b.y); o.w = pk2(b.z, b.w);
  *(uint4*)&out[i] = o;
}

// ---------------- wkv_b split: wb_k transposed per head, wb_v straight ----------------
__global__ __launch_bounds__(256) void prep_wkvb(const float* __restrict__ w,
                                                 u16* __restrict__ wbkt,
                                                 u16* __restrict__ wbv) {
  int idx = blockIdx.x * 256 + threadIdx.x;   // over 16*256*512
  int c = idx & 511;
  int rowh = idx >> 9;
  int h = rowh >> 8;
  int dr = rowh & 255;
  float v = w[idx];
  if (dr < NOPE) wbkt[((h * KVR + c) << 7) + dr] = f2b(v);           // (NH,512,128)
  else           wbv[((h * VH + (dr - NOPE)) << 9) + c] = f2b(v);    // (NH,128,512)
}

// ---------------- RMSNorm over 1024 (q path) ----------------
__global__ __launch_bounds__(256) void rms_q_kernel(const float* __restrict__ X,
                                                    const float* __restrict__ w,
                                                    u16* __restrict__ out) {
  int r = blockIdx.x, tid = threadIdx.x;
  const float4 v = *(const float4*)&X[(long)r * QR + tid * 4];
  float ss = v.x * v.x + v.y * v.y + v.z * v.z + v.w * v.w;
  for (int m = 1; m < 64; m <<= 1) ss += __shfl_xor(ss, m);
  __shared__ float red[4];
  if ((tid & 63) == 0) red[tid >> 6] = ss;
  __syncthreads();
  float tot = red[0] + red[1] + red[2] + red[3];
  float sc = rsqrtf(tot / QR + EPS_);
  float4 wv = *(const float4*)&w[tid * 4];
  uint2 o;
  o.x = pk2(v.x * sc * wv.x, v.y * sc * wv.y);
  o.y = pk2(v.z * sc * wv.z, v.w * sc * wv.w);
  *(uint2*)&out[(long)r * QR + tid * 4] = o;
}

// ---------------- q post (bf16 input): split nope / rope(pe)*SCALE, head-major ----------------
__global__ __launch_bounds__(256) void post_q_kernel(const u16* __restrict__ C2,
                                                     const float* __restrict__ fc,
                                                     const float* __restrict__ fs,
                                                     u16* __restrict__ qn,
                                                     u16* __restrict__ qp) {
  int r = blockIdx.x, tid = threadIdx.x;
  int s = r & (SS - 1);
  const u16* row = C2 + (long)r * (NH * QKH);
  for (int j = tid; j < NH * QKH / 2; j += 256) {
    int col = j * 2;
    int h = col / QKH;
    int dd = col - h * QKH;
    u32 pair = *(const u32*)&row[col];
    if (dd < NOPE) {
      *(u32*)&qn[((long)h * NTOK + r) * NOPE + dd] = pair;   // already bf16
    } else {
      float x0 = b2f(pair & 0xffffu), x1 = b2f(pair >> 16);
      int jr = (dd - NOPE) >> 1;
      float c = fc[s * 32 + jr], sn = fs[s * 32 + jr];
      *(u32*)&qp[((long)h * NTOK + r) * ROPE + (dd - NOPE)] =
          pk2((x0 * c - x1 * sn) * SCALE_, (x0 * sn + x1 * c) * SCALE_);
    }
  }
}

// ---------------- kv post: rmsnorm(512) -> kv_sw (XOR-swizzled) + v8 (k-subtiled), rope k_pe_sw ----
__global__ __launch_bounds__(256) void post_kv_kernel(const float* __restrict__ C3,
                                                      const float* __restrict__ w,
                                                      const float* __restrict__ fc,
                                                      const float* __restrict__ fs,
                                                      u16* __restrict__ kv_sw,
                                                      u16* __restrict__ v8,
                                                      u16* __restrict__ kpe_sw) {
  int r = blockIdx.x, tid = threadIdx.x;
  int b = r >> 10, t = r & (SS - 1);
  const float* row = C3 + (long)r * 576;
  float2 v = *(const float2*)&row[tid * 2];
  float ss = v.x * v.x + v.y * v.y;
  for (int m = 1; m < 64; m <<= 1) ss += __shfl_xor(ss, m);
  __shared__ float red[4];
  if ((tid & 63) == 0) red[tid >> 6] = ss;
  __syncthreads();
  float tot = red[0] + red[1] + red[2] + red[3];
  float sc = rsqrtf(tot / KVR + EPS_);
  int c = tid * 2;
  int xm = (t & 7) << 3;
  float y0 = v.x * sc * w[c], y1 = v.y * sc * w[c + 1];
  *(u32*)&kv_sw[((long)b * SS + t) * KVR + (c ^ xm)] = pk2(y0, y1);
  long o8 = (long)b * SS * KVR + ((long)(t >> 3) * 512 + c) * 8 + (t & 7);
  v8[o8]     = f2b(y0);
  v8[o8 + 8] = f2b(y1);
  if (tid < 32) {
    float x0 = row[KVR + tid * 2], x1 = row[KVR + tid * 2 + 1];
    float cc = fc[t * 32 + tid], sn = fs[t * 32 + tid];
    *(u32*)&kpe_sw[((long)b * SS + t) * ROPE + ((tid * 2) ^ xm)] =
        pk2(x0 * cc - x1 * sn, x0 * sn + x1 * cc);
  }
}

// ---------------- GEMM: C(M,N) = A(M,K) * B(N,K)^T, bf16 in, f32/bf16 out ----------------
// XCD-chunk swizzle: contiguous tile span per XCD (all grids have nwg%8==0).
template <bool CBF16>
__global__ __launch_bounds__(256) void gemm_bt(const u16* __restrict__ Ag,
                                               const u16* __restrict__ Bg,
                                               void* __restrict__ Cg,
                                               int M, int N, int K,
                                               int lda, int ldb, int ldc,
                                               long sA, long sB, long sC,
                                               float oscale) {
  const u16* A = Ag + (long)blockIdx.z * sA;
  const u16* Bm = Bg + (long)blockIdx.z * sB;
  const int nbx = gridDim.x;
  int bidf = blockIdx.y * nbx + blockIdx.x;
  {
    const int nwg = nbx * gridDim.y;
    if ((nwg & 7) == 0)
      bidf = (bidf & 7) * (nwg >> 3) + (bidf >> 3);   // bijective XCD chunks
  }
  const int row0 = (bidf / nbx) * 128;
  const int col0 = (bidf % nbx) * 128;
  const int tid = threadIdx.x;
  const int wave = tid >> 6, lane = tid & 63;
  const int g = lane >> 4, r = lane & 15;
  const int wr = wave >> 1, wc = wave & 1;

  __shared__ u16 As[2][128 * 32];
  __shared__ u16 Bs[2][128 * 32];

  f32x4 acc[4][4] = {};
  const int nk = K >> 5;

  auto stage = [&](int kt, int p) {
    int k0 = kt << 5;
#pragma unroll
    for (int j = 0; j < 2; ++j) {
      int ldsoff = (j * 4096 + wave * 1024) >> 1;
      int rowi = j * 64 + wave * 16 + (lane >> 2);
      int coli = (lane & 3) << 3;
      const u16* ga = A + (long)(row0 + rowi) * lda + k0 + coli;
      gll16(ga, &As[p][ldsoff]);
      int rb = col0 + rowi; if (rb > N - 1) rb = N - 1;
      const u16* gb = Bm + (long)rb * ldb + k0 + coli;
      gll16(gb, &Bs[p][ldsoff]);
    }
  };

  stage(0, 0);
  for (int kt = 0; kt < nk; ++kt) {
    __syncthreads();
    if (kt + 1 < nk) stage(kt + 1, (kt + 1) & 1);
    const int p = kt & 1;
    bf16x8 af[4], bf[4];
#pragma unroll
    for (int i = 0; i < 4; i++) {
      af[i] = *(const bf16x8*)&As[p][(wr * 64 + i * 16 + r) * 32 + g * 8];
      bf[i] = *(const bf16x8*)&Bs[p][(wc * 64 + i * 16 + r) * 32 + g * 8];
    }
#pragma unroll
    for (int i = 0; i < 4; i++)
#pragma unroll
      for (int j = 0; j < 4; j++)
        acc[i][j] = MFMA16(af[i], bf[j], acc[i][j], 0, 0, 0);
  }

#pragma unroll
  for (int i = 0; i < 4; i++)
#pragma unroll
    for (int j = 0; j < 4; j++) {
      int rowb = row0 + wr * 64 + i * 16 + g * 4;
      int colc = col0 + wc * 64 + j * 16 + r;
      if (colc < N) {
        if constexpr (CBF16) {
          u16* C = (u16*)Cg + (long)blockIdx.z * sC;
#pragma unroll
          for (int e = 0; e < 4; e++)
            C[(long)(rowb + e) * ldc + colc] = f2b(acc[i][j][e] * oscale);
        } else {
          float* C = (float*)Cg + (long)blockIdx.z * sC;
#pragma unroll
          for (int e = 0; e < 4; e++)
            C[(long)(rowb + e) * ldc + colc] = acc[i][j][e] * oscale;
        }
      }
    }
}

// ---------------- flash attention v12: round-9 structure + neutral micro-opts ----------------
// 512 blocks (4b x 16h x 8 chunk-pairs), 256 threads / 4 waves, 64 q-rows per
// block, paired chunks (j, 15-j) => 34 tiles/block. Single-buffer K/V/kpe (vf
// to regs before B1; stage(t+1) after B1, drained at B2). Classic rescale.
// Micro-opts vs r9: hoisted keb/kob XOR bases; nomask fast path (all but last
// 2 tiles). NO launch_bounds min-waves (r11 lesson: it forces spill).
__global__ __launch_bounds__(256) void attn_kernel(
    const u16* __restrict__ q_lat, const u16* __restrict__ q_pe,
    const u16* __restrict__ kv_sw, const u16* __restrict__ v8g,
    const u16* __restrict__ kpe_sw, u16* __restrict__ o_lat) {
  const int bid = blockIdx.x;
  const int xcd = bid & 7, idx = bid >> 3;
  const int b = xcd >> 1;
  const int h = idx & 15;
  const int jp = (idx >> 4) | ((xcd & 1) << 2);   // 0..7
  const int wv = threadIdx.x >> 6, lane = threadIdx.x & 63;
  const int g = lane >> 4, r = lane & 15;
  const int xm = (r & 7) << 3;
  // hoisted swizzle bases: (c*32+g*8)^xm == (c even ? keb : kob) + c*32
  const int keb = (g * 8) ^ xm;
  const int kob = keb - 2 * (xm & 32);

  __shared__ __attribute__((aligned(16))) u16 Ks[32 * 512];   // 32 KB swz K
  __shared__ __attribute__((aligned(16))) u16 Vs[32 * 512];   // 32 KB subtiled V
  __shared__ __attribute__((aligned(16))) u16 Kp[32 * 64];    // 4 KB swz kpe
  __shared__ __attribute__((aligned(16))) u16 P[64][40];      // 5 KB
  __shared__ float alphab[64];
  __shared__ float lbuf[64];

  const u16* KVg = kv_sw + (long)b * SS * KVR;
  const u16* VGg = v8g   + (long)b * SS * KVR;
  const u16* KPg = kpe_sw + (long)b * SS * ROPE;

  auto stage = [&](int t0) {
#pragma unroll
    for (int i = 0; i < 8; ++i) {
      int row = wv * 8 + i;
      gll16(KVg + (long)(t0 + row) * KVR + lane * 8, &Ks[row * 512]);
      gll16(VGg + (long)t0 * KVR + wv * 4096 + i * 512 + lane * 8,
            &Vs[wv * 4096 + i * 512]);
    }
    gll16(KPg + (long)t0 * ROPE + wv * 512 + lane * 8, &Kp[wv * 512]);
  };

  for (int seg = 0; seg < 2; ++seg) {
    const int j = seg ? jp : (15 - jp);    // big chunk first
    const int qa = j * 64;
    const int nt = 2 * (j + 1);            // 32-key tiles
    const int q_row = qa + wv * 16 + r;

    const u16* Q  = q_lat + ((long)h * NTOK + (long)b * SS + q_row) * KVR;
    const u16* Qp = q_pe  + ((long)h * NTOK + (long)b * SS + q_row) * ROPE;
    bf16x8 qf[18];
#pragma unroll
    for (int c = 0; c < 16; ++c) qf[c] = *(const bf16x8*)&Q[c * 32 + g * 8];
    qf[16] = *(const bf16x8*)&Qp[g * 8];
    qf[17] = *(const bf16x8*)&Qp[32 + g * 8];

    f32x4 acc[4][8];
#pragma unroll
    for (int i = 0; i < 4; i++)
#pragma unroll
      for (int jn = 0; jn < 8; jn++) acc[i][jn] = f32x4{0.f, 0.f, 0.f, 0.f};
    float m_run = -1e30f, l_run = 0.f;

    stage(0);
    __syncthreads();

    for (int tt = 0; tt < nt; ++tt) {
      const int t0 = tt << 5;

      // QK^T over 32 keys (2 row-groups of 16), 18 c-steps, imm-offset addrs
      f32x4 st0 = {0.f, 0.f, 0.f, 0.f}, st1 = {0.f, 0.f, 0.f, 0.f};
#pragma unroll
      for (int c = 0; c < 16; ++c) {
        int off = ((c & 1) ? kob : keb) + c * 32;
        bf16x8 k0 = *(const bf16x8*)&Ks[r * 512 + off];
        bf16x8 k1 = *(const bf16x8*)&Ks[(16 + r) * 512 + off];
        st0 = MFMA16(k0, qf[c], st0, 0, 0, 0);
        st1 = MFMA16(k1, qf[c], st1, 0, 0, 0);
      }
      {
        bf16x8 k0 = *(const bf16x8*)&Kp[r * 64 + keb];
        bf16x8 k1 = *(const bf16x8*)&Kp[(16 + r) * 64 + keb];
        st0 = MFMA16(k0, qf[16], st0, 0, 0, 0);
        st1 = MFMA16(k1, qf[16], st1, 0, 0, 0);
        bf16x8 k2 = *(const bf16x8*)&Kp[r * 64 + kob + 32];
        bf16x8 k3 = *(const bf16x8*)&Kp[(16 + r) * 64 + kob + 32];
        st0 = MFMA16(k2, qf[17], st0, 0, 0, 0);
        st1 = MFMA16(k3, qf[17], st1, 0, 0, 0);
      }

      // V fragments -> regs (must precede B1; stage overwrites Vs)
      bf16x8 vf[8];
#pragma unroll
      for (int nc = 0; nc < 8; ++nc)
        vf[nc] = *(const bf16x8*)&Vs[((g << 9) + (wv << 7) + (nc << 4) + r) << 3];

      // scores -> sv (mask only for last 2 tiles), row max
      float sv[8];
      float smax = -1e30f;
      if (t0 + 31 > qa) {
#pragma unroll
        for (int i = 0; i < 4; i++) {
          int t = t0 + g * 4 + i;
          sv[i]     = (t      <= q_row) ? st0[i] : -1e30f;
          sv[4 + i] = (t + 16 <= q_row) ? st1[i] : -1e30f;
          smax = fmaxf(smax, fmaxf(sv[i], sv[4 + i]));
        }
      } else {
#pragma unroll
        for (int i = 0; i < 4; i++) {
          sv[i] = st0[i]; sv[4 + i] = st1[i];
          smax = fmaxf(smax, fmaxf(sv[i], sv[4 + i]));
        }
      }
      smax = fmaxf(smax, __shfl_xor(smax, 16));
      smax = fmaxf(smax, __shfl_xor(smax, 32));
      float m_new = fmaxf(m_run, smax);
      float alpha = __expf(m_run - m_new);
      float ps = 0.f;
#pragma unroll
      for (int i = 0; i < 8; i++) {
        sv[i] = (sv[i] < -1e29f) ? 0.f : __expf(sv[i] - m_new);
        ps += sv[i];
      }
      ps += __shfl_xor(ps, 16);
      ps += __shfl_xor(ps, 32);
      l_run = l_run * alpha + ps;
      m_run = m_new;

      uint2 pw0, pw1;
      pw0.x = pk2(sv[0], sv[1]); pw0.y = pk2(sv[2], sv[3]);
      pw1.x = pk2(sv[4], sv[5]); pw1.y = pk2(sv[6], sv[7]);
      *(uint2*)&P[wv * 16 + r][g * 4]      = pw0;
      *(uint2*)&P[wv * 16 + r][16 + g * 4] = pw1;
      if (g == 0) alphab[wv * 16 + r] = alpha;
      __syncthreads();                   // B1: P/alpha visible; all LDS reads done
      if (tt + 1 < nt) stage(t0 + 32);   // overwrite K/V/kpe; drained at B2

      // PV: all 64 rows x own 128 cols (vf in regs)
#pragma unroll
      for (int mc = 0; mc < 4; ++mc) {
        bf16x8 pa = *(const bf16x8*)&P[mc * 16 + r][g * 8];
        f32x4 a4 = *(const f32x4*)&alphab[mc * 16 + g * 4];
#pragma unroll
        for (int nc = 0; nc < 8; ++nc) {
          f32x4 t = acc[mc][nc] * a4;
          acc[mc][nc] = MFMA16(pa, vf[nc], t, 0, 0, 0);
        }
      }
      __syncthreads();                   // B2: stage drained; P safe to rewrite
    }

    if (g == 0) lbuf[wv * 16 + r] = l_run;
    __syncthreads();
    u16* O = o_lat + ((long)h * NTOK + (long)b * SS + qa) * KVR;
#pragma unroll
    for (int mc = 0; mc < 4; ++mc) {
      f32x4 li = *(const f32x4*)&lbuf[mc * 16 + g * 4];
#pragma unroll
      for (int e = 0; e < 4; e++) li[e] = 1.f / li[e];
#pragma unroll
      for (int nc = 0; nc < 8; ++nc) {
        int col = wv * 128 + nc * 16 + r;
#pragma unroll
        for (int e = 0; e < 4; e++)
          O[(long)(mc * 16 + g * 4 + e) * KVR + col] = f2b(acc[mc][nc][e] * li[e]);
      }
    }
    __syncthreads();                     // lbuf/LDS safe for next seg
  }
}

// ---------------- host launch ----------------
extern "C" void kernel_launch(void* const* d_in, const int* in_sizes, int n_in,
                              void* d_out, int out_size, void* d_ws, size_t ws_size,
                              hipStream_t stream) {
  (void)in_sizes; (void)n_in; (void)out_size; (void)ws_size;
  const float* x    = (const float*)d_in[0];
  const float* fc   = (const float*)d_in[2];
  const float* fs   = (const float*)d_in[3];
  const float* wqa  = (const float*)d_in[4];
  const float* qnw  = (const float*)d_in[5];
  const float* wqb  = (const float*)d_in[6];
  const float* wkva = (const float*)d_in[7];
  const float* kvnw = (const float*)d_in[8];
  const float* wkvb = (const float*)d_in[9];
  const float* wo   = (const float*)d_in[10];
  float* out = (float*)d_out;

  char* w = (char*)d_ws;
  size_t off = 0;
  auto alloc = [&](size_t bytes) {
    void* p = w + off;
    off += (bytes + 255) & ~(size_t)255;
    return p;
  };
  // ---- persistent region ----
  u16* wbkt   = (u16*)alloc((size_t)NH * KVR * NOPE * 2);
  u16* wbv    = (u16*)alloc((size_t)NH * VH * KVR * 2);
  u16* wo_b   = (u16*)alloc((size_t)DIM * DIM * 2);
  u16* qnope  = (u16*)alloc((size_t)NH * NTOK * NOPE * 2);
  u16* qpe    = (u16*)alloc((size_t)NH * NTOK * ROPE * 2);
  u16* kv_sw  = (u16*)alloc((size_t)BB * SS * KVR * 2);
  u16* v8b    = (u16*)alloc((size_t)BB * SS * KVR * 2);
  u16* kpe_sw = (u16*)alloc((size_t)BB * SS * ROPE * 2);
  u16* oflat  = (u16*)alloc((size_t)NTOK * DIM * 2);
  // ---- transient region, later overlaid by qlat/olat ----
  u16* qlat   = (u16*)(w + off);            // overlay base
  u16* olat   = qlat;                       // attention writes O in-place over Q
  u16* x_bf   = (u16*)alloc((size_t)NTOK * DIM * 2);
  u16* wqa_b  = (u16*)alloc((size_t)QR * DIM * 2);
  u16* wqb_b  = (u16*)alloc((size_t)NH * QKH * QR * 2);
  u16* wkva_b = (u16*)alloc((size_t)576 * DIM * 2);
  u16* qn     = (u16*)alloc((size_t)NTOK * QR * 2);
  float* C1   = (float*)alloc((size_t)NTOK * QR * 4);
  u16* C2b    = (u16*)alloc((size_t)NTOK * NH * QKH * 2);

  cvt_bf16<<<(NTOK * DIM) / 2048, 256, 0, stream>>>(x, x_bf, NTOK * DIM);
  cvt_bf16<<<(QR * DIM) / 2048, 256, 0, stream>>>(wqa, wqa_b, QR * DIM);
  cvt_bf16<<<(NH * QKH * QR) / 2048, 256, 0, stream>>>(wqb, wqb_b, NH * QKH * QR);
  cvt_bf16<<<(576 * DIM) / 2048, 256, 0, stream>>>(wkva, wkva_b, 576 * DIM);
  cvt_bf16<<<(DIM * DIM) / 2048, 256, 0, stream>>>(wo, wo_b, DIM * DIM);
  prep_wkvb<<<(NH * 256 * KVR) / 256, 256, 0, stream>>>(wkvb, wbkt, wbv);

  gemm_bt<false><<<dim3(QR / 128, NTOK / 128, 1), 256, 0, stream>>>(
      x_bf, wqa_b, C1, NTOK, QR, DIM, DIM, DIM, QR, 0, 0, 0, 1.f);
  rms_q_kernel<<<NTOK, 256, 0, stream>>>(C1, qnw, qn);
  gemm_bt<true><<<dim3(NH * QKH / 128, NTOK / 128, 1), 256, 0, stream>>>(
      qn, wqb_b, C2b, NTOK, NH * QKH, QR, QR, QR, NH * QKH, 0, 0, 0, 1.f);
  post_q_kernel<<<NTOK, 256, 0, stream>>>(C2b, fc, fs, qnope, qpe);
  gemm_bt<false><<<dim3(5, NTOK / 128, 1), 256, 0, stream>>>(
      x_bf, wkva_b, C1, NTOK, 576, DIM, DIM, DIM, 576, 0, 0, 0, 1.f);
  post_kv_kernel<<<NTOK, 256, 0, stream>>>(C1, kvnw, fc, fs, kv_sw, v8b, kpe_sw);
  // q_lat pre-scaled by SCALE_ (softmax scale folded into Q)
  gemm_bt<true><<<dim3(KVR / 128, NTOK / 128, NH), 256, 0, stream>>>(
      qnope, wbkt, qlat, NTOK, KVR, NOPE, NOPE, NOPE, KVR,
      (long)NTOK * NOPE, (long)KVR * NOPE, (long)NTOK * KVR, SCALE_);
  attn_kernel<<<dim3(512, 1, 1), 256, 0, stream>>>(
      qlat, qpe, kv_sw, v8b, kpe_sw, olat);
  gemm_bt<true><<<dim3(1, NTOK / 128, NH), 256, 0, stream>>>(
      olat, wbv, oflat, NTOK, VH, KVR, KVR, KVR, DIM,
      (long)NTOK * KVR, (long)VH * KVR, (long)VH, 1.f);
  gemm_bt<false><<<dim3(DIM / 128, NTOK / 128, 1), 256, 0, stream>>>(
      oflat, wo_b, out, NTOK, DIM, DIM, DIM, DIM, DIM, 0, 0, 0, 1.f);
}

// Round 13
// 401.872 us; speedup vs baseline: 2.5194x; 1.1124x over previous
//
#include <hip/hip_runtime.h>
#include <hip/hip_bf16.h>
#include <stdint.h>

#define BB 4
#define SS 1024
#define DIM 2048
#define NH 16
#define QR 1024
#define KVR 512
#define NOPE 128
#define ROPE 64
#define VH 128
#define QKH 192
#define NTOK 4096
#define NFUSE 1600   // QR + 576

static constexpr float SCALE_ = 0.07216878364870322f; // 192^-0.5
static constexpr float EPS_ = 1e-6f;

typedef unsigned short u16;
typedef unsigned int u32;
using f32x4  = __attribute__((ext_vector_type(4))) float;
using bf16x8 = __attribute__((ext_vector_type(8))) __bf16;

#define MFMA16 __builtin_amdgcn_mfma_f32_16x16x32_bf16

__device__ __forceinline__ u16 f2b(float f) {
  u32 u = __float_as_uint(f);
  u32 r = u + 0x7fffu + ((u >> 16) & 1u);   // RNE
  return (u16)(r >> 16);
}
__device__ __forceinline__ u32 pk2(float a, float b) {
  return (u32)f2b(a) | ((u32)f2b(b) << 16);
}
__device__ __forceinline__ float b2f(u32 hi16) {
  return __uint_as_float(hi16 << 16);
}
__device__ __forceinline__ void gll16(const u16* g, u16* l) {
  __builtin_amdgcn_global_load_lds(
      (const __attribute__((address_space(1))) void*)g,
      (__attribute__((address_space(3))) void*)l, 16, 0, 0);
}

// ---------------- fused f32->bf16 conversions (6 regions, 1 launch) ----------------
// R0 x(8.4M) R1 wqa->wcat[0:1024) R2 wqb R3 wkva->wcat[1024:1600) R4 wo
// R5 wkvb v-half -> wbv (plain copy per head)
__global__ __launch_bounds__(256) void cvt_all(
    const float* __restrict__ x, u16* __restrict__ x_bf,
    const float* __restrict__ wqa, const float* __restrict__ wkva,
    u16* __restrict__ wcat,
    const float* __restrict__ wqb, u16* __restrict__ wqb_b,
    const float* __restrict__ wo, u16* __restrict__ wo_b,
    const float* __restrict__ wkvb, u16* __restrict__ wbv) {
  int bid = blockIdx.x;
  const float* src; u16* dst; long i;
  if (bid < 4096)      { src = x;    dst = x_bf;  i = (long)bid * 2048; }
  else if (bid < 5120) { src = wqa;  dst = wcat;  i = (long)(bid - 4096) * 2048; }
  else if (bid < 6656) { src = wqb;  dst = wqb_b; i = (long)(bid - 5120) * 2048; }
  else if (bid < 7232) { src = wkva; dst = wcat + (long)QR * DIM; i = (long)(bid - 6656) * 2048; }
  else if (bid < 9280) { src = wo;   dst = wo_b;  i = (long)(bid - 7232) * 2048; }
  else {  // wbv: head h, rem over (128 x 512)
    long e = (long)(bid - 9280) * 2048;
    int h = (int)(e >> 16);
    int rem = (int)(e & 65535);
    src = wkvb + (((long)h * 256 + 128) << 9) + rem;
    dst = wbv + ((long)h << 16) + rem;
    i = 0;
  }
  i += threadIdx.x * 8;
  float4 a = *(const float4*)&src[i];
  float4 b = *(const float4*)&src[i + 4];
  uint4 o;
  o.x = pk2(a.x, a.y); o.y = pk2(a.z, a.w);
  o.z = pk2(b.x, b.y); o.w = pk2(b.z, b.w);
  *(uint4*)&dst[i] = o;
}

// ---------------- wbkt transpose: (h, dr<128, c) -> wbkt (h, c, dr), coalesced via LDS ----------------
__global__ __launch_bounds__(256) void wbkt_tr(const float* __restrict__ wkvb,
                                               u16* __restrict__ wbkt) {
  const int c0 = blockIdx.x * 64, dr0 = blockIdx.y * 64, h = blockIdx.z;
  const int tid = threadIdx.x;
  __shared__ u16 L[64][72];
  {
    int row = tid >> 2, cq = (tid & 3) * 16;
    const float* p = wkvb + (((long)h * 256 + dr0 + row) << 9) + c0 + cq;
    float4 v0 = *(const float4*)&p[0];
    float4 v1 = *(const float4*)&p[4];
    float4 v2 = *(const float4*)&p[8];
    float4 v3 = *(const float4*)&p[12];
    uint2 w0, w1;
    w0.x = pk2(v0.x, v0.y); w0.y = pk2(v0.z, v0.w);
    w1.x = pk2(v1.x, v1.y); w1.y = pk2(v1.z, v1.w);
    *(uint2*)&L[row][cq]     = w0;
    *(uint2*)&L[row][cq + 4] = w1;
    w0.x = pk2(v2.x, v2.y); w0.y = pk2(v2.z, v2.w);
    w1.x = pk2(v3.x, v3.y); w1.y = pk2(v3.z, v3.w);
    *(uint2*)&L[row][cq + 8]  = w0;
    *(uint2*)&L[row][cq + 12] = w1;
  }
  __syncthreads();
  {
    int crow = tid >> 2, dq = (tid & 3) * 16;
    u16 tmp[16];
#pragma unroll
    for (int e = 0; e < 16; ++e) tmp[e] = L[dq + e][crow];
    u16* dst = wbkt + (((long)h * 512 + c0 + crow) << 7) + dr0 + dq;
    *(uint4*)&dst[0] = *(uint4*)&tmp[0];
    *(uint4*)&dst[8] = *(uint4*)&tmp[8];
  }
}

// ---------------- RMSNorm over 1024 (q path), C1 ldc=1600 ----------------
__global__ __launch_bounds__(256) void rms_q_kernel(const float* __restrict__ X,
                                                    const float* __restrict__ w,
                                                    u16* __restrict__ out) {
  int r = blockIdx.x, tid = threadIdx.x;
  const float4 v = *(const float4*)&X[(long)r * NFUSE + tid * 4];
  float ss = v.x * v.x + v.y * v.y + v.z * v.z + v.w * v.w;
  for (int m = 1; m < 64; m <<= 1) ss += __shfl_xor(ss, m);
  __shared__ float red[4];
  if ((tid & 63) == 0) red[tid >> 6] = ss;
  __syncthreads();
  float tot = red[0] + red[1] + red[2] + red[3];
  float sc = rsqrtf(tot / QR + EPS_);
  float4 wv = *(const float4*)&w[tid * 4];
  uint2 o;
  o.x = pk2(v.x * sc * wv.x, v.y * sc * wv.y);
  o.y = pk2(v.z * sc * wv.z, v.w * sc * wv.w);
  *(uint2*)&out[(long)r * QR + tid * 4] = o;
}

// ---------------- q post (bf16 input): split nope / rope(pe)*SCALE, head-major ----------------
__global__ __launch_bounds__(256) void post_q_kernel(const u16* __restrict__ C2,
                                                     const float* __restrict__ fc,
                                                     const float* __restrict__ fs,
                                                     u16* __restrict__ qn,
                                                     u16* __restrict__ qp) {
  int r = blockIdx.x, tid = threadIdx.x;
  int s = r & (SS - 1);
  const u16* row = C2 + (long)r * (NH * QKH);
  for (int j = tid; j < NH * QKH / 2; j += 256) {
    int col = j * 2;
    int h = col / QKH;
    int dd = col - h * QKH;
    u32 pair = *(const u32*)&row[col];
    if (dd < NOPE) {
      *(u32*)&qn[((long)h * NTOK + r) * NOPE + dd] = pair;   // already bf16
    } else {
      float x0 = b2f(pair & 0xffffu), x1 = b2f(pair >> 16);
      int jr = (dd - NOPE) >> 1;
      float c = fc[s * 32 + jr], sn = fs[s * 32 + jr];
      *(u32*)&qp[((long)h * NTOK + r) * ROPE + (dd - NOPE)] =
          pk2((x0 * c - x1 * sn) * SCALE_, (x0 * sn + x1 * c) * SCALE_);
    }
  }
}

// ---------------- kv post: rmsnorm(512) -> kv_sw (XOR-swizzled) + v8 (k-subtiled), rope k_pe_sw ----
// C1 row base offset 1024, ldc=1600.
__global__ __launch_bounds__(256) void post_kv_kernel(const float* __restrict__ C3,
                                                      const float* __restrict__ w,
                                                      const float* __restrict__ fc,
                                                      const float* __restrict__ fs,
                                                      u16* __restrict__ kv_sw,
                                                      u16* __restrict__ v8,
                                                      u16* __restrict__ kpe_sw) {
  int r = blockIdx.x, tid = threadIdx.x;
  int b = r >> 10, t = r & (SS - 1);
  const float* row = C3 + (long)r * NFUSE + QR;
  float2 v = *(const float2*)&row[tid * 2];
  float ss = v.x * v.x + v.y * v.y;
  for (int m = 1; m < 64; m <<= 1) ss += __shfl_xor(ss, m);
  __shared__ float red[4];
  if ((tid & 63) == 0) red[tid >> 6] = ss;
  __syncthreads();
  float tot = red[0] + red[1] + red[2] + red[3];
  float sc = rsqrtf(tot / KVR + EPS_);
  int c = tid * 2;
  int xm = (t & 7) << 3;
  float y0 = v.x * sc * w[c], y1 = v.y * sc * w[c + 1];
  *(u32*)&kv_sw[((long)b * SS + t) * KVR + (c ^ xm)] = pk2(y0, y1);
  long o8 = (long)b * SS * KVR + ((long)(t >> 3) * 512 + c) * 8 + (t & 7);
  v8[o8]     = f2b(y0);
  v8[o8 + 8] = f2b(y1);
  if (tid < 32) {
    float x0 = row[KVR + tid * 2], x1 = row[KVR + tid * 2 + 1];
    float cc = fc[t * 32 + tid], sn = fs[t * 32 + tid];
    *(u32*)&kpe_sw[((long)b * SS + t) * ROPE + ((tid * 2) ^ xm)] =
        pk2(x0 * cc - x1 * sn, x0 * sn + x1 * cc);
  }
}

// ---------------- GEMM: C(M,N) = A(M,K) * B(N,K)^T, bf16 in, f32/bf16 out ----------------
// XCD-chunk swizzle: contiguous tile span per XCD (all grids have nwg%8==0).
template <bool CBF16>
__global__ __launch_bounds__(256) void gemm_bt(const u16* __restrict__ Ag,
                                               const u16* __restrict__ Bg,
                                               void* __restrict__ Cg,
                                               int M, int N, int K,
                                               int lda, int ldb, int ldc,
                                               long sA, long sB, long sC,
                                               float oscale) {
  const u16* A = Ag + (long)blockIdx.z * sA;
  const u16* Bm = Bg + (long)blockIdx.z * sB;
  const int nbx = gridDim.x;
  int bidf = blockIdx.y * nbx + blockIdx.x;
  {
    const int nwg = nbx * gridDim.y;
    if ((nwg & 7) == 0)
      bidf = (bidf & 7) * (nwg >> 3) + (bidf >> 3);   // bijective XCD chunks
  }
  const int row0 = (bidf / nbx) * 128;
  const int col0 = (bidf % nbx) * 128;
  const int tid = threadIdx.x;
  const int wave = tid >> 6, lane = tid & 63;
  const int g = lane >> 4, r = lane & 15;
  const int wr = wave >> 1, wc = wave & 1;

  __shared__ u16 As[2][128 * 32];
  __shared__ u16 Bs[2][128 * 32];

  f32x4 acc[4][4] = {};
  const int nk = K >> 5;

  auto stage = [&](int kt, int p) {
    int k0 = kt << 5;
#pragma unroll
    for (int j = 0; j < 2; ++j) {
      int ldsoff = (j * 4096 + wave * 1024) >> 1;
      int rowi = j * 64 + wave * 16 + (lane >> 2);
      int coli = (lane & 3) << 3;
      const u16* ga = A + (long)(row0 + rowi) * lda + k0 + coli;
      gll16(ga, &As[p][ldsoff]);
      int rb = col0 + rowi; if (rb > N - 1) rb = N - 1;
      const u16* gb = Bm + (long)rb * ldb + k0 + coli;
      gll16(gb, &Bs[p][ldsoff]);
    }
  };

  stage(0, 0);
  for (int kt = 0; kt < nk; ++kt) {
    __syncthreads();
    if (kt + 1 < nk) stage(kt + 1, (kt + 1) & 1);
    const int p = kt & 1;
    bf16x8 af[4], bf[4];
#pragma unroll
    for (int i = 0; i < 4; i++) {
      af[i] = *(const bf16x8*)&As[p][(wr * 64 + i * 16 + r) * 32 + g * 8];
      bf[i] = *(const bf16x8*)&Bs[p][(wc * 64 + i * 16 + r) * 32 + g * 8];
    }
#pragma unroll
    for (int i = 0; i < 4; i++)
#pragma unroll
      for (int j = 0; j < 4; j++)
        acc[i][j] = MFMA16(af[i], bf[j], acc[i][j], 0, 0, 0);
  }

#pragma unroll
  for (int i = 0; i < 4; i++)
#pragma unroll
    for (int j = 0; j < 4; j++) {
      int rowb = row0 + wr * 64 + i * 16 + g * 4;
      int colc = col0 + wc * 64 + j * 16 + r;
      if (colc < N) {
        if constexpr (CBF16) {
          u16* C = (u16*)Cg + (long)blockIdx.z * sC;
#pragma unroll
          for (int e = 0; e < 4; e++)
            C[(long)(rowb + e) * ldc + colc] = f2b(acc[i][j][e] * oscale);
        } else {
          float* C = (float*)Cg + (long)blockIdx.z * sC;
#pragma unroll
          for (int e = 0; e < 4; e++)
            C[(long)(rowb + e) * ldc + colc] = acc[i][j][e] * oscale;
        }
      }
    }
}

// ---------------- flash attention v12 (unchanged from round 12) ----------------
__global__ __launch_bounds__(256) void attn_kernel(
    const u16* __restrict__ q_lat, const u16* __restrict__ q_pe,
    const u16* __restrict__ kv_sw, const u16* __restrict__ v8g,
    const u16* __restrict__ kpe_sw, u16* __restrict__ o_lat) {
  const int bid = blockIdx.x;
  const int xcd = bid & 7, idx = bid >> 3;
  const int b = xcd >> 1;
  const int h = idx & 15;
  const int jp = (idx >> 4) | ((xcd & 1) << 2);   // 0..7
  const int wv = threadIdx.x >> 6, lane = threadIdx.x & 63;
  const int g = lane >> 4, r = lane & 15;
  const int xm = (r & 7) << 3;
  const int keb = (g * 8) ^ xm;
  const int kob = keb - 2 * (xm & 32);

  __shared__ __attribute__((aligned(16))) u16 Ks[32 * 512];   // 32 KB swz K
  __shared__ __attribute__((aligned(16))) u16 Vs[32 * 512];   // 32 KB subtiled V
  __shared__ __attribute__((aligned(16))) u16 Kp[32 * 64];    // 4 KB swz kpe
  __shared__ __attribute__((aligned(16))) u16 P[64][40];      // 5 KB
  __shared__ float alphab[64];
  __shared__ float lbuf[64];

  const u16* KVg = kv_sw + (long)b * SS * KVR;
  const u16* VGg = v8g   + (long)b * SS * KVR;
  const u16* KPg = kpe_sw + (long)b * SS * ROPE;

  auto stage = [&](int t0) {
#pragma unroll
    for (int i = 0; i < 8; ++i) {
      int row = wv * 8 + i;
      gll16(KVg + (long)(t0 + row) * KVR + lane * 8, &Ks[row * 512]);
      gll16(VGg + (long)t0 * KVR + wv * 4096 + i * 512 + lane * 8,
            &Vs[wv * 4096 + i * 512]);
    }
    gll16(KPg + (long)t0 * ROPE + wv * 512 + lane * 8, &Kp[wv * 512]);
  };

  for (int seg = 0; seg < 2; ++seg) {
    const int j = seg ? jp : (15 - jp);    // big chunk first
    const int qa = j * 64;
    const int nt = 2 * (j + 1);            // 32-key tiles
    const int q_row = qa + wv * 16 + r;

    const u16* Q  = q_lat + ((long)h * NTOK + (long)b * SS + q_row) * KVR;
    const u16* Qp = q_pe  + ((long)h * NTOK + (long)b * SS + q_row) * ROPE;
    bf16x8 qf[18];
#pragma unroll
    for (int c = 0; c < 16; ++c) qf[c] = *(const bf16x8*)&Q[c * 32 + g * 8];
    qf[16] = *(const bf16x8*)&Qp[g * 8];
    qf[17] = *(const bf16x8*)&Qp[32 + g * 8];

    f32x4 acc[4][8];
#pragma unroll
    for (int i = 0; i < 4; i++)
#pragma unroll
      for (int jn = 0; jn < 8; jn++) acc[i][jn] = f32x4{0.f, 0.f, 0.f, 0.f};
    float m_run = -1e30f, l_run = 0.f;

    stage(0);
    __syncthreads();

    for (int tt = 0; tt < nt; ++tt) {
      const int t0 = tt << 5;

      f32x4 st0 = {0.f, 0.f, 0.f, 0.f}, st1 = {0.f, 0.f, 0.f, 0.f};
#pragma unroll
      for (int c = 0; c < 16; ++c) {
        int off = ((c & 1) ? kob : keb) + c * 32;
        bf16x8 k0 = *(const bf16x8*)&Ks[r * 512 + off];
        bf16x8 k1 = *(const bf16x8*)&Ks[(16 + r) * 512 + off];
        st0 = MFMA16(k0, qf[c], st0, 0, 0, 0);
        st1 = MFMA16(k1, qf[c], st1, 0, 0, 0);
      }
      {
        bf16x8 k0 = *(const bf16x8*)&Kp[r * 64 + keb];
        bf16x8 k1 = *(const bf16x8*)&Kp[(16 + r) * 64 + keb];
        st0 = MFMA16(k0, qf[16], st0, 0, 0, 0);
        st1 = MFMA16(k1, qf[16], st1, 0, 0, 0);
        bf16x8 k2 = *(const bf16x8*)&Kp[r * 64 + kob + 32];
        bf16x8 k3 = *(const bf16x8*)&Kp[(16 + r) * 64 + kob + 32];
        st0 = MFMA16(k2, qf[17], st0, 0, 0, 0);
        st1 = MFMA16(k3, qf[17], st1, 0, 0, 0);
      }

      bf16x8 vf[8];
#pragma unroll
      for (int nc = 0; nc < 8; ++nc)
        vf[nc] = *(const bf16x8*)&Vs[((g << 9) + (wv << 7) + (nc << 4) + r) << 3];

      float sv[8];
      float smax = -1e30f;
      if (t0 + 31 > qa) {
#pragma unroll
        for (int i = 0; i < 4; i++) {
          int t = t0 + g * 4 + i;
          sv[i]     = (t      <= q_row) ? st0[i] : -1e30f;
          sv[4 + i] = (t + 16 <= q_row) ? st1[i] : -1e30f;
          smax = fmaxf(smax, fmaxf(sv[i], sv[4 + i]));
        }
      } else {
#pragma unroll
        for (int i = 0; i < 4; i++) {
          sv[i] = st0[i]; sv[4 + i] = st1[i];
          smax = fmaxf(smax, fmaxf(sv[i], sv[4 + i]));
        }
      }
      smax = fmaxf(smax, __shfl_xor(smax, 16));
      smax = fmaxf(smax, __shfl_xor(smax, 32));
      float m_new = fmaxf(m_run, smax);
      float alpha = __expf(m_run - m_new);
      float ps = 0.f;
#pragma unroll
      for (int i = 0; i < 8; i++) {
        sv[i] = (sv[i] < -1e29f) ? 0.f : __expf(sv[i] - m_new);
        ps += sv[i];
      }
      ps += __shfl_xor(ps, 16);
      ps += __shfl_xor(ps, 32);
      l_run = l_run * alpha + ps;
      m_run = m_new;

      uint2 pw0, pw1;
      pw0.x = pk2(sv[0], sv[1]); pw0.y = pk2(sv[2], sv[3]);
      pw1.x = pk2(sv[4], sv[5]); pw1.y = pk2(sv[6], sv[7]);
      *(uint2*)&P[wv * 16 + r][g * 4]      = pw0;
      *(uint2*)&P[wv * 16 + r][16 + g * 4] = pw1;
      if (g == 0) alphab[wv * 16 + r] = alpha;
      __syncthreads();                   // B1: P/alpha visible; all LDS reads done
      if (tt + 1 < nt) stage(t0 + 32);   // overwrite K/V/kpe; drained at B2

#pragma unroll
      for (int mc = 0; mc < 4; ++mc) {
        bf16x8 pa = *(const bf16x8*)&P[mc * 16 + r][g * 8];
        f32x4 a4 = *(const f32x4*)&alphab[mc * 16 + g * 4];
#pragma unroll
        for (int nc = 0; nc < 8; ++nc) {
          f32x4 t = acc[mc][nc] * a4;
          acc[mc][nc] = MFMA16(pa, vf[nc], t, 0, 0, 0);
        }
      }
      __syncthreads();                   // B2: stage drained; P safe to rewrite
    }

    if (g == 0) lbuf[wv * 16 + r] = l_run;
    __syncthreads();
    u16* O = o_lat + ((long)h * NTOK + (long)b * SS + qa) * KVR;
#pragma unroll
    for (int mc = 0; mc < 4; ++mc) {
      f32x4 li = *(const f32x4*)&lbuf[mc * 16 + g * 4];
#pragma unroll
      for (int e = 0; e < 4; e++) li[e] = 1.f / li[e];
#pragma unroll
      for (int nc = 0; nc < 8; ++nc) {
        int col = wv * 128 + nc * 16 + r;
#pragma unroll
        for (int e = 0; e < 4; e++)
          O[(long)(mc * 16 + g * 4 + e) * KVR + col] = f2b(acc[mc][nc][e] * li[e]);
      }
    }
    __syncthreads();                     // lbuf/LDS safe for next seg
  }
}

// ---------------- host launch ----------------
extern "C" void kernel_launch(void* const* d_in, const int* in_sizes, int n_in,
                              void* d_out, int out_size, void* d_ws, size_t ws_size,
                              hipStream_t stream) {
  (void)in_sizes; (void)n_in; (void)out_size; (void)ws_size;
  const float* x    = (const float*)d_in[0];
  const float* fc   = (const float*)d_in[2];
  const float* fs   = (const float*)d_in[3];
  const float* wqa  = (const float*)d_in[4];
  const float* qnw  = (const float*)d_in[5];
  const float* wqb  = (const float*)d_in[6];
  const float* wkva = (const float*)d_in[7];
  const float* kvnw = (const float*)d_in[8];
  const float* wkvb = (const float*)d_in[9];
  const float* wo   = (const float*)d_in[10];
  float* out = (float*)d_out;

  char* w = (char*)d_ws;
  size_t off = 0;
  auto alloc = [&](size_t bytes) {
    void* p = w + off;
    off += (bytes + 255) & ~(size_t)255;
    return p;
  };
  // ---- persistent region ----
  u16* wbkt   = (u16*)alloc((size_t)NH * KVR * NOPE * 2);
  u16* wbv    = (u16*)alloc((size_t)NH * VH * KVR * 2);
  u16* wo_b   = (u16*)alloc((size_t)DIM * DIM * 2);
  u16* qnope  = (u16*)alloc((size_t)NH * NTOK * NOPE * 2);
  u16* qpe    = (u16*)alloc((size_t)NH * NTOK * ROPE * 2);
  u16* kv_sw  = (u16*)alloc((size_t)BB * SS * KVR * 2);
  u16* v8b    = (u16*)alloc((size_t)BB * SS * KVR * 2);
  u16* kpe_sw = (u16*)alloc((size_t)BB * SS * ROPE * 2);
  u16* oflat  = (u16*)alloc((size_t)NTOK * DIM * 2);
  // ---- transient region, later overlaid by qlat/olat ----
  u16* qlat   = (u16*)(w + off);            // overlay base
  u16* olat   = qlat;                       // attention writes O in-place over Q
  u16* x_bf   = (u16*)alloc((size_t)NTOK * DIM * 2);
  u16* wcat   = (u16*)alloc((size_t)NFUSE * DIM * 2);
  u16* wqb_b  = (u16*)alloc((size_t)NH * QKH * QR * 2);
  u16* qn     = (u16*)alloc((size_t)NTOK * QR * 2);
  float* C1   = (float*)alloc((size_t)NTOK * NFUSE * 4);
  u16* C2b    = (u16*)alloc((size_t)NTOK * NH * QKH * 2);

  // fused conversions (1 launch) + wbkt transpose
  cvt_all<<<9792, 256, 0, stream>>>(x, x_bf, wqa, wkva, wcat, wqb, wqb_b,
                                    wo, wo_b, wkvb, wbv);
  wbkt_tr<<<dim3(8, 2, 16), 256, 0, stream>>>(wkvb, wbkt);

  // fused [q_a | kv_full] = x @ [wq_a; wkv_a]^T   (4096 x 1600, K=2048)
  gemm_bt<false><<<dim3(13, NTOK / 128, 1), 256, 0, stream>>>(
      x_bf, wcat, C1, NTOK, NFUSE, DIM, DIM, DIM, NFUSE, 0, 0, 0, 1.f);
  rms_q_kernel<<<NTOK, 256, 0, stream>>>(C1, qnw, qn);
  gemm_bt<true><<<dim3(NH * QKH / 128, NTOK / 128, 1), 256, 0, stream>>>(
      qn, wqb_b, C2b, NTOK, NH * QKH, QR, QR, QR, NH * QKH, 0, 0, 0, 1.f);
  post_q_kernel<<<NTOK, 256, 0, stream>>>(C2b, fc, fs, qnope, qpe);
  post_kv_kernel<<<NTOK, 256, 0, stream>>>(C1, kvnw, fc, fs, kv_sw, v8b, kpe_sw);
  // q_lat pre-scaled by SCALE_ (softmax scale folded into Q)
  gemm_bt<true><<<dim3(KVR / 128, NTOK / 128, NH), 256, 0, stream>>>(
      qnope, wbkt, qlat, NTOK, KVR, NOPE, NOPE, NOPE, KVR,
      (long)NTOK * NOPE, (long)KVR * NOPE, (long)NTOK * KVR, SCALE_);
  attn_kernel<<<dim3(512, 1, 1), 256, 0, stream>>>(
      qlat, qpe, kv_sw, v8b, kpe_sw, olat);
  gemm_bt<true><<<dim3(1, NTOK / 128, NH), 256, 0, stream>>>(
      olat, wbv, oflat, NTOK, VH, KVR, KVR, KVR, DIM,
      (long)NTOK * KVR, (long)VH * KVR, (long)VH, 1.f);
  gemm_bt<false><<<dim3(DIM / 128, NTOK / 128, 1), 256, 0, stream>>>(
      oflat, wo_b, out, NTOK, DIM, DIM, DIM, DIM, DIM, 0, 0, 0, 1.f);
}